// Round 12
// baseline (481.195 us; speedup 1.0000x reference)
//
#include <hip/hip_runtime.h>
#include <hip/hip_bf16.h>
#include <hip/hip_fp16.h>
#include <cstdint>

typedef _Float16 f16;
typedef _Float16 f16x8 __attribute__((ext_vector_type(8)));
typedef _Float16 f16x4 __attribute__((ext_vector_type(4)));
typedef float f32x4 __attribute__((ext_vector_type(4)));

#define DEV_INLINE __device__ __forceinline__

// async 16B/lane global->LDS. LDS dest is wave-uniform base + lane*16.
DEV_INLINE void async_ld16(const void* g, void* l) {
  __builtin_amdgcn_global_load_lds((const __attribute__((address_space(1))) void*)g,
                                   (__attribute__((address_space(3))) void*)l, 16, 0, 0);
}

template <int N>
DEV_INLINE void wait_vm() {
  static_assert(N >= 0 && N <= 12, "gate range");
  if constexpr (N == 0)  asm volatile("s_waitcnt vmcnt(0)" ::: "memory");
  if constexpr (N == 1)  asm volatile("s_waitcnt vmcnt(1)" ::: "memory");
  if constexpr (N == 2)  asm volatile("s_waitcnt vmcnt(2)" ::: "memory");
  if constexpr (N == 3)  asm volatile("s_waitcnt vmcnt(3)" ::: "memory");
  if constexpr (N == 4)  asm volatile("s_waitcnt vmcnt(4)" ::: "memory");
  if constexpr (N == 5)  asm volatile("s_waitcnt vmcnt(5)" ::: "memory");
  if constexpr (N == 6)  asm volatile("s_waitcnt vmcnt(6)" ::: "memory");
  if constexpr (N == 7)  asm volatile("s_waitcnt vmcnt(7)" ::: "memory");
  if constexpr (N == 8)  asm volatile("s_waitcnt vmcnt(8)" ::: "memory");
  if constexpr (N == 9)  asm volatile("s_waitcnt vmcnt(9)" ::: "memory");
  if constexpr (N == 10) asm volatile("s_waitcnt vmcnt(10)" ::: "memory");
  if constexpr (N == 11) asm volatile("s_waitcnt vmcnt(11)" ::: "memory");
  if constexpr (N == 12) asm volatile("s_waitcnt vmcnt(12)" ::: "memory");
}
DEV_INLINE void lgk0() {
  asm volatile("s_waitcnt lgkmcnt(0)" ::: "memory");
  __builtin_amdgcn_sched_barrier(0);
}

// ---------------- merged prep: x hi/lo split + Wcat cast + bias/scale ----------------
__global__ __launch_bounds__(256) void k_prep_all(
    const float* __restrict__ x,
    const int* __restrict__ wq, const int* __restrict__ wk, const int* __restrict__ wv,
    const float* __restrict__ bq, const float* __restrict__ bk, const float* __restrict__ bv,
    const float* __restrict__ sq, const float* __restrict__ sk, const float* __restrict__ sv,
    f16* __restrict__ acat, f16* __restrict__ wcat,
    float* __restrict__ bias_cat, float* __restrict__ scale_cat) {
  const int bid = blockIdx.x;
  if (bid < 8192) {
    int i = (bid * 256 + threadIdx.x) * 4;  // exactly covers 2048*4096
    float4 v = *(const float4*)&x[i];
    int row = i >> 12, col = i & 4095;
    f16 h0 = (f16)v.x, h1 = (f16)v.y, h2 = (f16)v.z, h3 = (f16)v.w;
    f16x4 hi = {h0, h1, h2, h3};
    f16x4 lo = {(f16)(v.x - (float)h0), (f16)(v.y - (float)h1),
                (f16)(v.z - (float)h2), (f16)(v.w - (float)h3)};
    size_t base = (size_t)row * 8192 + col;
    *(f16x4*)&acat[base] = hi;
    *(f16x4*)&acat[base + 4096] = lo;
  } else {
    int i = (bid - 8192) * 256 + threadIdx.x;
    if (i < 6291456) {
      int e = i * 4, row = e >> 12, col = e & 4095;
      int4 v;
      if (row < 4096)      v = *(const int4*)&wq[(size_t)row * 4096 + col];
      else if (row < 5120) v = *(const int4*)&wk[(size_t)(row - 4096) * 4096 + col];
      else                 v = *(const int4*)&wv[(size_t)(row - 5120) * 4096 + col];
      f16x4 o = {(f16)(float)v.x, (f16)(float)v.y, (f16)(float)v.z, (f16)(float)v.w};
      *(f16x4*)&wcat[e] = o;
    }
    if (i < 6144) {
      float b, s;
      if (i < 4096)      { b = bq[i];        s = sq[0]; }
      else if (i < 5120) { b = bk[i - 4096]; s = sk[0]; }
      else               { b = bv[i - 5120]; s = sv[0]; }
      bias_cat[i] = b;
      scale_cat[i] = s;
    }
  }
}

// int32 weights (values in [-127,127], exact in f16) -> f16
__global__ __launch_bounds__(256) void k_cast_i32_f16(const int* __restrict__ w,
                                                      f16* __restrict__ out, int n) {
  int i = (blockIdx.x * 256 + threadIdx.x) * 4;
  if (i >= n) return;
  int4 v = *(const int4*)&w[i];
  f16x4 o = {(f16)(float)v.x, (f16)(float)v.y, (f16)(float)v.z, (f16)(float)v.w};
  *(f16x4*)&out[i] = o;
}

// ---------------- GEMM v8: 2 merged phases per K-tile (24 MFMA per barrier-pair) ----------------
// C[M,N] = A[M,K] * W[N,ldw]^T, k wraps by kmask on the W side.
// 512 threads = 8 waves (2M x 4N). BK=64 double-buffered LDS, 4 barriers/K-tile.
// Phase A(t): stage {Ak1(t+1), Bk1(t+1)} (kc1 regions, last read B(t-1));
//             read A.kc0(t) + B.kc0(t); gate vmcnt(GS); bar; lgk0; 24 MFMA; bar.
// Phase B(t): stage {Ak0(t+2), Bk0(t+2)} (kc0 regions, last read A(t));
//             read A.kc1(t) + B.kc1(t); gate vmcnt(GS); bar; lgk0; 24 MFMA; bar.
// Gates derived from issue stream (Ak before Bk in each phase):
//   steady GS = 2*(LA+LB); tails GS -> LA+LB -> 0. Gate->barrier->read invariant:
//   each phase's reads were certified by the PREVIOUS phase's gate + its barriers.
// Overwrite safety: every staged region's last reads retired at the prior
//   phase's lgk0, and all waves passed that phase's closing barrier first.
template <int BM, int BN, int MODE>
__global__ __launch_bounds__(512) void k_gemm8(
    const f16* __restrict__ A, const f16* __restrict__ W,
    f16* __restrict__ o_hi, f16* __restrict__ o_lo, float* __restrict__ o_f32,
    const float* __restrict__ scale_vec, const float* __restrict__ bias_vec,
    const float* __restrict__ scale_scalar,
    int N, int K, int kmask, int ldw, int nym) {
  constexpr int WM = 2, WN = 4;
  constexpr int MR = BM / WM / 16;      // 4
  constexpr int NR = BN / WN / 16;      // 6 (qkv) / 4 (oproj)
  constexpr int AKC = BM * 64;          // bytes per A kc-block
  constexpr int BKC = BN * 64;
  constexpr int SLOT = 2 * (AKC + BKC);
  constexpr int LAH = AKC / 8192;       // 1
  constexpr int LBH = BKC / 8192;       // 3 / 2
  constexpr int GS = 2 * (LAH + LBH);   // 8 / 6
  constexpr int G1 = LAH + LBH;         // 4 / 3
  extern __shared__ __align__(16) char lds[];

  const int t = threadIdx.x, w = t >> 6, ln = t & 63;
  const int lr = ln & 15, lg = ln >> 4;
  const int wn = w & 3, wm = w >> 2;

  // T1: bijective XCD swizzle (m204)
  const int nwg = gridDim.x;
  const int q8 = nwg >> 3, r8 = nwg & 7;
  const int xcd = blockIdx.x & 7, bidx = blockIdx.x >> 3;
  const int sid = (xcd < r8 ? xcd * (q8 + 1) : r8 * (q8 + 1) + (xcd - r8) * q8) + bidx;
  const int m0 = (sid % nym) * BM;
  const int n0 = (sid / nym) * BN;

  const f16* aSrc[LAH];
  const f16* bSrc[LBH];
#pragma unroll
  for (int l = 0; l < LAH; l++) {
    int ci = l * 512 + t, row = ci >> 2, c = ci & 3;
    aSrc[l] = A + (size_t)(m0 + row) * K + (c ^ ((row >> 1) & 3)) * 8;
  }
#pragma unroll
  for (int l = 0; l < LBH; l++) {
    int ci = l * 512 + t, row = ci >> 2, c = ci & 3;
    bSrc[l] = W + (size_t)(n0 + row) * ldw + (c ^ ((row >> 1) & 3)) * 8;
  }

  f32x4 acc[MR][NR] = {};
  f16x8 af[MR], bfa[NR];

  auto stageA = [&](int tt, int kc) {
    char* dst = lds + (tt & 1) * SLOT + kc * AKC;
    const int ko = tt * 64 + kc * 32;
#pragma unroll
    for (int l = 0; l < LAH; l++)
      async_ld16(aSrc[l] + ko, dst + (l * 512 + w * 64) * 16);
  };
  auto stageB = [&](int tt, int kc) {
    char* dst = lds + (tt & 1) * SLOT + 2 * AKC + kc * BKC;
    const int ko = ((tt * 64) & kmask) + kc * 32;
#pragma unroll
    for (int l = 0; l < LBH; l++)
      async_ld16(bSrc[l] + ko, dst + (l * 512 + w * 64) * 16);
  };
  auto readA = [&](int tt, int kc) {
    const char* base = lds + (tt & 1) * SLOT + kc * AKC;
#pragma unroll
    for (int mf = 0; mf < MR; mf++) {
      const int row = wm * (BM / WM) + mf * 16 + lr;
      af[mf] = *(const f16x8*)(base + row * 64 + (lg ^ ((row >> 1) & 3)) * 16);
    }
  };
  auto readBall = [&](int tt, int kc) {
    const char* base = lds + (tt & 1) * SLOT + 2 * AKC + kc * BKC;
#pragma unroll
    for (int nf = 0; nf < NR; nf++) {
      const int row = wn * (BN / WN) + nf * 16 + lr;
      bfa[nf] = *(const f16x8*)(base + row * 64 + (lg ^ ((row >> 1) & 3)) * 16);
    }
  };
  auto mma = [&]() {
    __builtin_amdgcn_s_setprio(1);
#pragma unroll
    for (int m = 0; m < MR; m++)
#pragma unroll
      for (int n = 0; n < NR; n++)
        acc[m][n] = __builtin_amdgcn_mfma_f32_16x16x32_f16(af[m], bfa[n], acc[m][n], 0, 0, 0);
    __builtin_amdgcn_s_setprio(0);
  };
  auto bar = [&]() { __builtin_amdgcn_s_barrier(); };

  const int NT = K >> 6;
  // prologue stream: Ak0(0) Bk0(0) Ak1(0) Bk1(0) Ak0(1) Bk0(1);
  // gate (after Bk0(0)): Ak1(0)+Bk1(0)+Ak0(1)+Bk0(1) = GS
  stageA(0, 0); stageB(0, 0); stageA(0, 1); stageB(0, 1);
  stageA(1, 0); stageB(1, 0);
  wait_vm<GS>();
  bar();

  for (int tt = 0; tt + 2 < NT; ++tt) {
    // phase A: kc0
    stageA(tt + 1, 1); stageB(tt + 1, 1);
    readA(tt, 0); readBall(tt, 0);
    wait_vm<GS>();      // certifies Ak1(tt),Bk1(tt) for phase B
    bar(); lgk0(); mma(); bar();
    // phase B: kc1
    stageA(tt + 2, 0); stageB(tt + 2, 0);
    readA(tt, 1); readBall(tt, 1);
    wait_vm<GS>();      // certifies Ak0(tt+1),Bk0(tt+1) for next phase A
    bar(); lgk0(); mma(); bar();
  }
  {  // tt = NT-2: phase A stages kc1(NT-1); phase B stages nothing
    const int tt = NT - 2;
    stageA(tt + 1, 1); stageB(tt + 1, 1);
    readA(tt, 0); readBall(tt, 0);
    wait_vm<GS>();      // certifies Ak1(NT-2),Bk1(NT-2)
    bar(); lgk0(); mma(); bar();
    readA(tt, 1); readBall(tt, 1);
    wait_vm<G1>();      // certifies Ak0(NT-1),Bk0(NT-1)
    bar(); lgk0(); mma(); bar();
  }
  {  // tt = NT-1: drain
    const int tt = NT - 1;
    readA(tt, 0); readBall(tt, 0);
    wait_vm<0>();       // certifies Ak1(NT-1),Bk1(NT-1)
    bar(); lgk0(); mma(); bar();
    readA(tt, 1); readBall(tt, 1);
    lgk0(); mma();      // kc1(NT-1) certified by the vmcnt(0)+barrier above
  }

#pragma unroll
  for (int n = 0; n < NR; n++) {
    const int col = n0 + wn * (BN / WN) + n * 16 + lr;
    const float sc = (MODE == 0) ? scale_vec[col] : scale_scalar[0];
    const float bs = (MODE == 0) ? bias_vec[col] : 0.f;
#pragma unroll
    for (int m = 0; m < MR; m++)
#pragma unroll
      for (int r2 = 0; r2 < 4; r2++) {
        const int row = m0 + wm * (BM / WM) + m * 16 + lg * 4 + r2;
        const float v = acc[m][n][r2] * sc + bs;
        if constexpr (MODE == 0) {
          f16 h = (f16)v;
          o_hi[(size_t)row * N + col] = h;
          o_lo[(size_t)row * N + col] = (f16)(v - (float)h);
        } else {
          o_f32[(size_t)row * N + col] = v;
        }
      }
  }
}

// ---------------- RoPE v2: f16x4-vectorized (4 pairs/thread), f32 math ----------------
__global__ __launch_bounds__(256) void k_rope2(f16* __restrict__ XH, f16* __restrict__ XL,
                                               const float* __restrict__ cosT,
                                               const float* __restrict__ sinT,
                                               const int* __restrict__ sp) {
  int idx = blockIdx.x * 256 + threadIdx.x;  // 2048 tokens * 40 heads * 16 quads
  if (idx >= 2048 * 40 * 16) return;
  int c4 = (idx & 15) * 4;
  int hh = (idx >> 4) % 40;
  int tkn = idx / (40 * 16);
  int col = (hh < 32) ? hh * 128 : 4096 + (hh - 32) * 128;
  size_t i1 = (size_t)tkn * 6144 + col + c4, i2 = i1 + 64;
  int pos = (tkn & 1023) + sp[0];
  const float4 cv = *(const float4*)&cosT[pos * 128 + c4];
  const float4 sv = *(const float4*)&sinT[pos * 128 + c4];
  f16x4 xh1 = *(const f16x4*)&XH[i1], xh2 = *(const f16x4*)&XH[i2];
  f16x4 xl1 = *(const f16x4*)&XL[i1], xl2 = *(const f16x4*)&XL[i2];
  f16x4 oh1, ol1, oh2, ol2;
  const float cc[4] = {cv.x, cv.y, cv.z, cv.w};
  const float ss[4] = {sv.x, sv.y, sv.z, sv.w};
#pragma unroll
  for (int i = 0; i < 4; i++) {
    float x1 = (float)xh1[i] + (float)xl1[i];
    float x2 = (float)xh2[i] + (float)xl2[i];
    float o1 = x1 * cc[i] - x2 * ss[i];
    float o2 = x2 * cc[i] + x1 * ss[i];
    f16 h1 = (f16)o1, h2 = (f16)o2;
    oh1[i] = h1; ol1[i] = (f16)(o1 - (float)h1);
    oh2[i] = h2; ol2[i] = (f16)(o2 - (float)h2);
  }
  *(f16x4*)&XH[i1] = oh1; *(f16x4*)&XL[i1] = ol1;
  *(f16x4*)&XH[i2] = oh2; *(f16x4*)&XL[i2] = ol2;
}

// ---------------- flash attention v4: QBLK=128, kvh-pinned, reg-prefetch K/V ----------------
__global__ __launch_bounds__(512) void k_attn4(const f16* __restrict__ XH,
                                               const f16* __restrict__ XL,
                                               f16* __restrict__ out) {
  __shared__ __align__(16) f16 KsH[32 * 152];
  __shared__ __align__(16) f16 KsL[32 * 152];
  __shared__ __align__(16) f16 VT[128 * 40];
  __shared__ __align__(16) f16 Pb[8 * 16 * 40];
  const int t = threadIdx.x, w = t >> 6, l = t & 63;
  const int lr = l & 15, lg = l >> 4;
  // id = ((b*4 + hg)*8 + qb)*8 + kvh  -> blocks sharing (b,kvh) pin to one XCD
  const int id = blockIdx.x;
  const int kvh = id & 7;
  const int j = id >> 3;
  const int qb = j & 7;
  const int hg = (j >> 3) & 3;
  const int b = j >> 5;
  const int h = kvh * 4 + hg;
  const int q0 = qb * 128;
  const size_t rs_ = 6144;
  const f16* Qh = XH + ((size_t)(b * 1024 + q0)) * rs_ + h * 128;
  const f16* Ql_ = XL + ((size_t)(b * 1024 + q0)) * rs_ + h * 128;
  const f16* KhG = XH + ((size_t)(b * 1024)) * rs_ + 4096 + kvh * 128;
  const f16* KlG = XL + ((size_t)(b * 1024)) * rs_ + 4096 + kvh * 128;
  const f16* VG = XH + ((size_t)(b * 1024)) * rs_ + 5120 + kvh * 128;

  f16x8 qh[4], ql[4];
  {
    size_t qoff = (size_t)(w * 16 + lr) * rs_ + lg * 8;
#pragma unroll
    for (int c = 0; c < 4; c++) {
      qh[c] = *(const f16x8*)(Qh + qoff + c * 32);
      ql[c] = *(const f16x8*)(Ql_ + qoff + c * 32);
    }
  }
  f32x4 accd[8] = {};
  float m_r[4], l_r[4];
#pragma unroll
  for (int r = 0; r < 4; r++) { m_r[r] = -1e30f; l_r[r] = 0.f; }

  const int krow_s = t >> 4, kch = t & 15;
  const int vrow_s = t & 31, vd8 = t >> 5;
  f16x8 khr, klr, vr;
  auto loadKV = [&](int kv0) {
    size_t go = (size_t)(kv0 + krow_s) * rs_ + kch * 8;
    khr = *(const f16x8*)(KhG + go);
    klr = *(const f16x8*)(KlG + go);
    vr = *(const f16x8*)(VG + (size_t)(kv0 + vrow_s) * rs_ + vd8 * 8);
  };
  auto writeKV = [&]() {
    *(f16x8*)&KsH[krow_s * 152 + kch * 8] = khr;
    *(f16x8*)&KsL[krow_s * 152 + kch * 8] = klr;
#pragma unroll
    for (int jj = 0; jj < 8; jj++) VT[(vd8 * 8 + jj) * 40 + vrow_s] = vr[jj];
  };

  const int nkv = q0 + 128;
  const int NT = nkv >> 5;
  loadKV(0);
  wait_vm<0>();
  writeKV();
  __syncthreads();

  for (int tt = 0; tt < NT; ++tt) {
    const int kv0 = tt * 32;
    const bool pf = (tt + 1 < NT);
    if (pf) {
      loadKV(kv0 + 32);
      __builtin_amdgcn_sched_barrier(0);
    }

    f32x4 sc[2] = {};
#pragma unroll
    for (int cb = 0; cb < 2; cb++)
#pragma unroll
      for (int c = 0; c < 4; c++) {
        const f16x8 kh = *(const f16x8*)&KsH[(cb * 16 + lr) * 152 + c * 32 + lg * 8];
        const f16x8 kl = *(const f16x8*)&KsL[(cb * 16 + lr) * 152 + c * 32 + lg * 8];
        sc[cb] = __builtin_amdgcn_mfma_f32_16x16x32_f16(qh[c], kh, sc[cb], 0, 0, 0);
        sc[cb] = __builtin_amdgcn_mfma_f32_16x16x32_f16(qh[c], kl, sc[cb], 0, 0, 0);
        sc[cb] = __builtin_amdgcn_mfma_f32_16x16x32_f16(ql[c], kh, sc[cb], 0, 0, 0);
      }

    const float scale = 0.088388347648318447f;
    float alpha[4], pv[2][4];
#pragma unroll
    for (int r = 0; r < 4; r++) {
      const int qg = q0 + w * 16 + lg * 4 + r;
      float mx = -1e30f;
#pragma unroll
      for (int cb = 0; cb < 2; cb++) {
        const int kg = kv0 + cb * 16 + lr;
        float s = sc[cb][r] * scale;
        s = (kg <= qg) ? s : -1e30f;
        pv[cb][r] = s;
        mx = fmaxf(mx, s);
      }
      mx = fmaxf(mx, __shfl_xor(mx, 1));
      mx = fmaxf(mx, __shfl_xor(mx, 2));
      mx = fmaxf(mx, __shfl_xor(mx, 4));
      mx = fmaxf(mx, __shfl_xor(mx, 8));
      const float mn = fmaxf(m_r[r], mx);
      alpha[r] = __expf(m_r[r] - mn);
      m_r[r] = mn;
      float rsum = 0.f;
#pragma unroll
      for (int cb = 0; cb < 2; cb++) {
        const int kg = kv0 + cb * 16 + lr;
        const float p = (kg <= qg) ? __expf(pv[cb][r] - mn) : 0.f;
        pv[cb][r] = p;
        rsum += p;
      }
      rsum += __shfl_xor(rsum, 1);
      rsum += __shfl_xor(rsum, 2);
      rsum += __shfl_xor(rsum, 4);
      rsum += __shfl_xor(rsum, 8);
      l_r[r] = l_r[r] * alpha[r] + rsum;
    }

    f16* Pw = &Pb[w * 16 * 40];
#pragma unroll
    for (int r = 0; r < 4; r++)
#pragma unroll
      for (int cb = 0; cb < 2; cb++)
        Pw[(lg * 4 + r) * 40 + cb * 16 + lr] = (f16)pv[cb][r];
    const f16x8 pf_ = *(const f16x8*)&Pw[lr * 40 + lg * 8];

#pragma unroll
    for (int dc = 0; dc < 8; dc++) {
      const f16x8 vf = *(const f16x8*)&VT[(dc * 16 + lr) * 40 + lg * 8];
#pragma unroll
      for (int r = 0; r < 4; r++) accd[dc][r] *= alpha[r];
      accd[dc] = __builtin_amdgcn_mfma_f32_16x16x32_f16(pf_, vf, accd[dc], 0, 0, 0);
    }

    __syncthreads();
    if (pf) writeKV();
    __syncthreads();
  }

#pragma unroll
  for (int dc = 0; dc < 8; dc++)
#pragma unroll
    for (int r = 0; r < 4; r++) {
      const int row = b * 1024 + q0 + w * 16 + lg * 4 + r;
      out[(size_t)row * 4096 + h * 128 + dc * 16 + lr] = (f16)(accd[dc][r] / l_r[r]);
    }
}

// ---------------- launch ----------------
extern "C" void kernel_launch(void* const* d_in, const int* in_sizes, int n_in,
                              void* d_out, int out_size, void* d_ws, size_t ws_size,
                              hipStream_t stream) {
  const float* x = (const float*)d_in[0];
  const float* cosT = (const float*)d_in[2];
  const float* sinT = (const float*)d_in[3];
  const int* wq = (const int*)d_in[4];
  const float* bq = (const float*)d_in[5];
  const float* sq = (const float*)d_in[6];
  const int* wk = (const int*)d_in[7];
  const float* bk = (const float*)d_in[8];
  const float* sk = (const float*)d_in[9];
  const int* wv = (const int*)d_in[10];
  const float* bv = (const float*)d_in[11];
  const float* sv = (const float*)d_in[12];
  const int* wo = (const int*)d_in[13];
  const float* so = (const float*)d_in[14];
  const int* sp = (const int*)d_in[15];

  char* ws = (char*)d_ws;
  f16* Acat = (f16*)ws;                        // x hi|lo [2048][8192]; later reused for Wo
  f16* Wcat = (f16*)(ws + 33554432);           // wq|wk|wv f16 [6144][4096]
  f16* XH = (f16*)(ws + 83886080);             // qkv hi [2048][6144]
  f16* XL = (f16*)(ws + 109051904);            // qkv lo
  f16* AO = (f16*)(ws + 134217728);            // attn out [2048][4096]
  float* biasv = (float*)(ws + 150994944);
  float* scalev = (float*)(ws + 151019520);

  hipFuncSetAttribute(reinterpret_cast<const void*>(&k_gemm8<128, 384, 0>),
                      hipFuncAttributeMaxDynamicSharedMemorySize, 131072);
  hipFuncSetAttribute(reinterpret_cast<const void*>(&k_gemm8<128, 256, 1>),
                      hipFuncAttributeMaxDynamicSharedMemorySize, 98304);

  k_prep_all<<<32768, 256, 0, stream>>>(x, wq, wk, wv, bq, bk, bv, sq, sk, sv,
                                        Acat, Wcat, biasv, scalev);

  // fused QKV projection (split-x, K=8192, W k-index wraps at 4096)
  k_gemm8<128, 384, 0><<<256, 512, 131072, stream>>>(
      Acat, Wcat, XH, XL, nullptr, scalev, biasv, nullptr, 6144, 8192, 4095, 4096, 16);

  k_rope2<<<5120, 256, 0, stream>>>(XH, XL, cosT, sinT, sp);

  f16* Wo_ = Acat;  // Acat dead after QKV GEMM
  k_cast_i32_f16<<<16384, 256, 0, stream>>>(wo, Wo_, 16777216);

  // attention: 512 blocks (QBLK=128), kvh-pinned XCD swizzle, reg-prefetch
  k_attn4<<<512, 512, 0, stream>>>(XH, XL, AO);

  // output projection -> f32; 16 x 16 = 256 blocks = exactly 1/CU
  k_gemm8<128, 256, 1><<<256, 512, 98304, stream>>>(
      AO, Wo_, nullptr, nullptr, (float*)d_out, nullptr, nullptr, so, 4096, 4096,
      0x7fffffff, 4096, 16);
}

// Round 13
// 476.577 us; speedup vs baseline: 1.0097x; 1.0097x over previous
//
#include <hip/hip_runtime.h>
#include <hip/hip_bf16.h>
#include <hip/hip_fp16.h>
#include <cstdint>

typedef _Float16 f16;
typedef _Float16 f16x8 __attribute__((ext_vector_type(8)));
typedef _Float16 f16x4 __attribute__((ext_vector_type(4)));
typedef float f32x4 __attribute__((ext_vector_type(4)));

#define DEV_INLINE __device__ __forceinline__

// async 16B/lane global->LDS. LDS dest is wave-uniform base + lane*16.
DEV_INLINE void async_ld16(const void* g, void* l) {
  __builtin_amdgcn_global_load_lds((const __attribute__((address_space(1))) void*)g,
                                   (__attribute__((address_space(3))) void*)l, 16, 0, 0);
}

template <int N>
DEV_INLINE void wait_vm() {
  static_assert(N >= 0 && N <= 12, "gate range");
  if constexpr (N == 0)  asm volatile("s_waitcnt vmcnt(0)" ::: "memory");
  if constexpr (N == 1)  asm volatile("s_waitcnt vmcnt(1)" ::: "memory");
  if constexpr (N == 2)  asm volatile("s_waitcnt vmcnt(2)" ::: "memory");
  if constexpr (N == 3)  asm volatile("s_waitcnt vmcnt(3)" ::: "memory");
  if constexpr (N == 4)  asm volatile("s_waitcnt vmcnt(4)" ::: "memory");
  if constexpr (N == 5)  asm volatile("s_waitcnt vmcnt(5)" ::: "memory");
  if constexpr (N == 6)  asm volatile("s_waitcnt vmcnt(6)" ::: "memory");
  if constexpr (N == 7)  asm volatile("s_waitcnt vmcnt(7)" ::: "memory");
  if constexpr (N == 8)  asm volatile("s_waitcnt vmcnt(8)" ::: "memory");
  if constexpr (N == 9)  asm volatile("s_waitcnt vmcnt(9)" ::: "memory");
  if constexpr (N == 10) asm volatile("s_waitcnt vmcnt(10)" ::: "memory");
  if constexpr (N == 11) asm volatile("s_waitcnt vmcnt(11)" ::: "memory");
  if constexpr (N == 12) asm volatile("s_waitcnt vmcnt(12)" ::: "memory");
}
DEV_INLINE void lgk0() {
  asm volatile("s_waitcnt lgkmcnt(0)" ::: "memory");
  __builtin_amdgcn_sched_barrier(0);
}

// ---------------- merged prep: x hi/lo split + Wcat cast + bias/scale ----------------
__global__ __launch_bounds__(256) void k_prep_all(
    const float* __restrict__ x,
    const int* __restrict__ wq, const int* __restrict__ wk, const int* __restrict__ wv,
    const float* __restrict__ bq, const float* __restrict__ bk, const float* __restrict__ bv,
    const float* __restrict__ sq, const float* __restrict__ sk, const float* __restrict__ sv,
    f16* __restrict__ acat, f16* __restrict__ wcat,
    float* __restrict__ bias_cat, float* __restrict__ scale_cat) {
  const int bid = blockIdx.x;
  if (bid < 8192) {
    int i = (bid * 256 + threadIdx.x) * 4;  // exactly covers 2048*4096
    float4 v = *(const float4*)&x[i];
    int row = i >> 12, col = i & 4095;
    f16 h0 = (f16)v.x, h1 = (f16)v.y, h2 = (f16)v.z, h3 = (f16)v.w;
    f16x4 hi = {h0, h1, h2, h3};
    f16x4 lo = {(f16)(v.x - (float)h0), (f16)(v.y - (float)h1),
                (f16)(v.z - (float)h2), (f16)(v.w - (float)h3)};
    size_t base = (size_t)row * 8192 + col;
    *(f16x4*)&acat[base] = hi;
    *(f16x4*)&acat[base + 4096] = lo;
  } else {
    int i = (bid - 8192) * 256 + threadIdx.x;
    if (i < 6291456) {
      int e = i * 4, row = e >> 12, col = e & 4095;
      int4 v;
      if (row < 4096)      v = *(const int4*)&wq[(size_t)row * 4096 + col];
      else if (row < 5120) v = *(const int4*)&wk[(size_t)(row - 4096) * 4096 + col];
      else                 v = *(const int4*)&wv[(size_t)(row - 5120) * 4096 + col];
      f16x4 o = {(f16)(float)v.x, (f16)(float)v.y, (f16)(float)v.z, (f16)(float)v.w};
      *(f16x4*)&wcat[e] = o;
    }
    if (i < 6144) {
      float b, s;
      if (i < 4096)      { b = bq[i];        s = sq[0]; }
      else if (i < 5120) { b = bk[i - 4096]; s = sk[0]; }
      else               { b = bv[i - 5120]; s = sv[0]; }
      bias_cat[i] = b;
      scale_cat[i] = s;
    }
  }
}

// int32 weights (values in [-127,127], exact in f16) -> f16
__global__ __launch_bounds__(256) void k_cast_i32_f16(const int* __restrict__ w,
                                                      f16* __restrict__ out, int n) {
  int i = (blockIdx.x * 256 + threadIdx.x) * 4;
  if (i >= n) return;
  int4 v = *(const int4*)&w[i];
  f16x4 o = {(f16)(float)v.x, (f16)(float)v.y, (f16)(float)v.z, (f16)(float)v.w};
  *(f16x4*)&out[i] = o;
}

// ---------------- GEMM v9: v8 body (proven) + fused-RoPE epilogue in MODE 0 ----------------
// Body identical to round-12 k_gemm8 (2 merged phases, gate->barrier->read).
// MODE 0 epilogue: BN=384 = 3 whole heads per tile (head-aligned). The f32
// results are exchanged through a [64][385] f32 LDS buffer (2 row-passes,
// 98KB <= 131KB dynamic LDS), rotated with cos/sin (cols < 5120 only; V cols
// pass through), then hi/lo-split and stored coalesced. Eliminates the
// separate rope kernel and its 80MB of XH/XL read+rewrite traffic.
template <int BM, int BN, int MODE>
__global__ __launch_bounds__(512) void k_gemm9(
    const f16* __restrict__ A, const f16* __restrict__ W,
    f16* __restrict__ o_hi, f16* __restrict__ o_lo, float* __restrict__ o_f32,
    const float* __restrict__ scale_vec, const float* __restrict__ bias_vec,
    const float* __restrict__ scale_scalar,
    const float* __restrict__ cosT, const float* __restrict__ sinT,
    const int* __restrict__ sp,
    int N, int K, int kmask, int ldw, int nym) {
  constexpr int WM = 2, WN = 4;
  constexpr int MR = BM / WM / 16;      // 4
  constexpr int NR = BN / WN / 16;      // 6 (qkv) / 4 (oproj)
  constexpr int AKC = BM * 64;          // bytes per A kc-block
  constexpr int BKC = BN * 64;
  constexpr int SLOT = 2 * (AKC + BKC);
  constexpr int LAH = AKC / 8192;       // 1
  constexpr int LBH = BKC / 8192;       // 3 / 2
  constexpr int GS = 2 * (LAH + LBH);   // 8 / 6
  constexpr int G1 = LAH + LBH;         // 4 / 3
  extern __shared__ __align__(16) char lds[];

  const int t = threadIdx.x, w = t >> 6, ln = t & 63;
  const int lr = ln & 15, lg = ln >> 4;
  const int wn = w & 3, wm = w >> 2;

  // T1: bijective XCD swizzle (m204)
  const int nwg = gridDim.x;
  const int q8 = nwg >> 3, r8 = nwg & 7;
  const int xcd = blockIdx.x & 7, bidx = blockIdx.x >> 3;
  const int sid = (xcd < r8 ? xcd * (q8 + 1) : r8 * (q8 + 1) + (xcd - r8) * q8) + bidx;
  const int m0 = (sid % nym) * BM;
  const int n0 = (sid / nym) * BN;

  const f16* aSrc[LAH];
  const f16* bSrc[LBH];
#pragma unroll
  for (int l = 0; l < LAH; l++) {
    int ci = l * 512 + t, row = ci >> 2, c = ci & 3;
    aSrc[l] = A + (size_t)(m0 + row) * K + (c ^ ((row >> 1) & 3)) * 8;
  }
#pragma unroll
  for (int l = 0; l < LBH; l++) {
    int ci = l * 512 + t, row = ci >> 2, c = ci & 3;
    bSrc[l] = W + (size_t)(n0 + row) * ldw + (c ^ ((row >> 1) & 3)) * 8;
  }

  f32x4 acc[MR][NR] = {};
  f16x8 af[MR], bfa[NR];

  auto stageA = [&](int tt, int kc) {
    char* dst = lds + (tt & 1) * SLOT + kc * AKC;
    const int ko = tt * 64 + kc * 32;
#pragma unroll
    for (int l = 0; l < LAH; l++)
      async_ld16(aSrc[l] + ko, dst + (l * 512 + w * 64) * 16);
  };
  auto stageB = [&](int tt, int kc) {
    char* dst = lds + (tt & 1) * SLOT + 2 * AKC + kc * BKC;
    const int ko = ((tt * 64) & kmask) + kc * 32;
#pragma unroll
    for (int l = 0; l < LBH; l++)
      async_ld16(bSrc[l] + ko, dst + (l * 512 + w * 64) * 16);
  };
  auto readA = [&](int tt, int kc) {
    const char* base = lds + (tt & 1) * SLOT + kc * AKC;
#pragma unroll
    for (int mf = 0; mf < MR; mf++) {
      const int row = wm * (BM / WM) + mf * 16 + lr;
      af[mf] = *(const f16x8*)(base + row * 64 + (lg ^ ((row >> 1) & 3)) * 16);
    }
  };
  auto readBall = [&](int tt, int kc) {
    const char* base = lds + (tt & 1) * SLOT + 2 * AKC + kc * BKC;
#pragma unroll
    for (int nf = 0; nf < NR; nf++) {
      const int row = wn * (BN / WN) + nf * 16 + lr;
      bfa[nf] = *(const f16x8*)(base + row * 64 + (lg ^ ((row >> 1) & 3)) * 16);
    }
  };
  auto mma = [&]() {
    __builtin_amdgcn_s_setprio(1);
#pragma unroll
    for (int m = 0; m < MR; m++)
#pragma unroll
      for (int n = 0; n < NR; n++)
        acc[m][n] = __builtin_amdgcn_mfma_f32_16x16x32_f16(af[m], bfa[n], acc[m][n], 0, 0, 0);
    __builtin_amdgcn_s_setprio(0);
  };
  auto bar = [&]() { __builtin_amdgcn_s_barrier(); };

  const int NT = K >> 6;
  stageA(0, 0); stageB(0, 0); stageA(0, 1); stageB(0, 1);
  stageA(1, 0); stageB(1, 0);
  wait_vm<GS>();
  bar();

  for (int tt = 0; tt + 2 < NT; ++tt) {
    stageA(tt + 1, 1); stageB(tt + 1, 1);
    readA(tt, 0); readBall(tt, 0);
    wait_vm<GS>();
    bar(); lgk0(); mma(); bar();
    stageA(tt + 2, 0); stageB(tt + 2, 0);
    readA(tt, 1); readBall(tt, 1);
    wait_vm<GS>();
    bar(); lgk0(); mma(); bar();
  }
  {
    const int tt = NT - 2;
    stageA(tt + 1, 1); stageB(tt + 1, 1);
    readA(tt, 0); readBall(tt, 0);
    wait_vm<GS>();
    bar(); lgk0(); mma(); bar();
    readA(tt, 1); readBall(tt, 1);
    wait_vm<G1>();
    bar(); lgk0(); mma(); bar();
  }
  {
    const int tt = NT - 1;
    readA(tt, 0); readBall(tt, 0);
    wait_vm<0>();
    bar(); lgk0(); mma(); bar();
    readA(tt, 1); readBall(tt, 1);
    lgk0(); mma();
  }

  if constexpr (MODE == 0) {
    // fused RoPE epilogue (BM=128, BN=384 = 3 heads, head-aligned)
    float* xch = (float*)lds;             // [64][385] f32, padded
    const int sp0 = sp[0];
    for (int pass = 0; pass < 2; ++pass) {
      bar();  // all waves done with prior lds use (K-loop reads / prev pass)
      if (wm == pass) {
#pragma unroll
        for (int n = 0; n < NR; n++) {
          const int col = wn * (BN / WN) + n * 16 + lr;
          const float sc = scale_vec[n0 + col];
          const float bs = bias_vec[n0 + col];
#pragma unroll
          for (int m = 0; m < MR; m++)
#pragma unroll
            for (int r2 = 0; r2 < 4; r2++) {
              const int row = m * 16 + lg * 4 + r2;  // 0..63 within pass
              xch[row * 385 + col] = acc[m][n][r2] * sc + bs;
            }
        }
      }
      bar();  // xch visible to all
      // cooperative rope+split+store: element idx = j*512 + t, coalesced cols
      for (int j = 0; j < (64 * BN) / 512; j++) {
        const int idx = j * 512 + t;
        const int r = idx / BN;
        const int c = idx - r * BN;
        const int gr = m0 + pass * 64 + r;
        const int gcol = n0 + c;
        float v = xch[r * 385 + c];
        float o;
        if (gcol < 5120) {  // Q,K heads get RoPE; V cols pass through
          const int q = c & 127;
          const int pos = (gr & 1023) + sp0;
          const float cs = cosT[pos * 128 + q];
          const float sn = sinT[pos * 128 + q];
          const float vp = xch[r * 385 + ((q < 64) ? c + 64 : c - 64)];
          o = (q < 64) ? v * cs - vp * sn : v * cs + vp * sn;
        } else {
          o = v;
        }
        f16 h = (f16)o;
        o_hi[(size_t)gr * N + gcol] = h;
        o_lo[(size_t)gr * N + gcol] = (f16)(o - (float)h);
      }
    }
  } else {
#pragma unroll
    for (int n = 0; n < NR; n++) {
      const int col = n0 + wn * (BN / WN) + n * 16 + lr;
      const float sc = scale_scalar[0];
#pragma unroll
      for (int m = 0; m < MR; m++)
#pragma unroll
        for (int r2 = 0; r2 < 4; r2++) {
          const int row = m0 + wm * (BM / WM) + m * 16 + lg * 4 + r2;
          o_f32[(size_t)row * N + col] = acc[m][n][r2] * sc;
        }
    }
  }
}

// ---------------- flash attention v4: QBLK=128, kvh-pinned, reg-prefetch K/V ----------------
__global__ __launch_bounds__(512) void k_attn4(const f16* __restrict__ XH,
                                               const f16* __restrict__ XL,
                                               f16* __restrict__ out) {
  __shared__ __align__(16) f16 KsH[32 * 152];
  __shared__ __align__(16) f16 KsL[32 * 152];
  __shared__ __align__(16) f16 VT[128 * 40];
  __shared__ __align__(16) f16 Pb[8 * 16 * 40];
  const int t = threadIdx.x, w = t >> 6, l = t & 63;
  const int lr = l & 15, lg = l >> 4;
  // id = ((b*4 + hg)*8 + qb)*8 + kvh  -> blocks sharing (b,kvh) pin to one XCD
  const int id = blockIdx.x;
  const int kvh = id & 7;
  const int j = id >> 3;
  const int qb = j & 7;
  const int hg = (j >> 3) & 3;
  const int b = j >> 5;
  const int h = kvh * 4 + hg;
  const int q0 = qb * 128;
  const size_t rs_ = 6144;
  const f16* Qh = XH + ((size_t)(b * 1024 + q0)) * rs_ + h * 128;
  const f16* Ql_ = XL + ((size_t)(b * 1024 + q0)) * rs_ + h * 128;
  const f16* KhG = XH + ((size_t)(b * 1024)) * rs_ + 4096 + kvh * 128;
  const f16* KlG = XL + ((size_t)(b * 1024)) * rs_ + 4096 + kvh * 128;
  const f16* VG = XH + ((size_t)(b * 1024)) * rs_ + 5120 + kvh * 128;

  f16x8 qh[4], ql[4];
  {
    size_t qoff = (size_t)(w * 16 + lr) * rs_ + lg * 8;
#pragma unroll
    for (int c = 0; c < 4; c++) {
      qh[c] = *(const f16x8*)(Qh + qoff + c * 32);
      ql[c] = *(const f16x8*)(Ql_ + qoff + c * 32);
    }
  }
  f32x4 accd[8] = {};
  float m_r[4], l_r[4];
#pragma unroll
  for (int r = 0; r < 4; r++) { m_r[r] = -1e30f; l_r[r] = 0.f; }

  const int krow_s = t >> 4, kch = t & 15;
  const int vrow_s = t & 31, vd8 = t >> 5;
  f16x8 khr, klr, vr;
  auto loadKV = [&](int kv0) {
    size_t go = (size_t)(kv0 + krow_s) * rs_ + kch * 8;
    khr = *(const f16x8*)(KhG + go);
    klr = *(const f16x8*)(KlG + go);
    vr = *(const f16x8*)(VG + (size_t)(kv0 + vrow_s) * rs_ + vd8 * 8);
  };
  auto writeKV = [&]() {
    *(f16x8*)&KsH[krow_s * 152 + kch * 8] = khr;
    *(f16x8*)&KsL[krow_s * 152 + kch * 8] = klr;
#pragma unroll
    for (int jj = 0; jj < 8; jj++) VT[(vd8 * 8 + jj) * 40 + vrow_s] = vr[jj];
  };

  const int nkv = q0 + 128;
  const int NT = nkv >> 5;
  loadKV(0);
  wait_vm<0>();
  writeKV();
  __syncthreads();

  for (int tt = 0; tt < NT; ++tt) {
    const int kv0 = tt * 32;
    const bool pf = (tt + 1 < NT);
    if (pf) {
      loadKV(kv0 + 32);
      __builtin_amdgcn_sched_barrier(0);
    }

    f32x4 sc[2] = {};
#pragma unroll
    for (int cb = 0; cb < 2; cb++)
#pragma unroll
      for (int c = 0; c < 4; c++) {
        const f16x8 kh = *(const f16x8*)&KsH[(cb * 16 + lr) * 152 + c * 32 + lg * 8];
        const f16x8 kl = *(const f16x8*)&KsL[(cb * 16 + lr) * 152 + c * 32 + lg * 8];
        sc[cb] = __builtin_amdgcn_mfma_f32_16x16x32_f16(qh[c], kh, sc[cb], 0, 0, 0);
        sc[cb] = __builtin_amdgcn_mfma_f32_16x16x32_f16(qh[c], kl, sc[cb], 0, 0, 0);
        sc[cb] = __builtin_amdgcn_mfma_f32_16x16x32_f16(ql[c], kh, sc[cb], 0, 0, 0);
      }

    const float scale = 0.088388347648318447f;
    float alpha[4], pv[2][4];
#pragma unroll
    for (int r = 0; r < 4; r++) {
      const int qg = q0 + w * 16 + lg * 4 + r;
      float mx = -1e30f;
#pragma unroll
      for (int cb = 0; cb < 2; cb++) {
        const int kg = kv0 + cb * 16 + lr;
        float s = sc[cb][r] * scale;
        s = (kg <= qg) ? s : -1e30f;
        pv[cb][r] = s;
        mx = fmaxf(mx, s);
      }
      mx = fmaxf(mx, __shfl_xor(mx, 1));
      mx = fmaxf(mx, __shfl_xor(mx, 2));
      mx = fmaxf(mx, __shfl_xor(mx, 4));
      mx = fmaxf(mx, __shfl_xor(mx, 8));
      const float mn = fmaxf(m_r[r], mx);
      alpha[r] = __expf(m_r[r] - mn);
      m_r[r] = mn;
      float rsum = 0.f;
#pragma unroll
      for (int cb = 0; cb < 2; cb++) {
        const int kg = kv0 + cb * 16 + lr;
        const float p = (kg <= qg) ? __expf(pv[cb][r] - mn) : 0.f;
        pv[cb][r] = p;
        rsum += p;
      }
      rsum += __shfl_xor(rsum, 1);
      rsum += __shfl_xor(rsum, 2);
      rsum += __shfl_xor(rsum, 4);
      rsum += __shfl_xor(rsum, 8);
      l_r[r] = l_r[r] * alpha[r] + rsum;
    }

    f16* Pw = &Pb[w * 16 * 40];
#pragma unroll
    for (int r = 0; r < 4; r++)
#pragma unroll
      for (int cb = 0; cb < 2; cb++)
        Pw[(lg * 4 + r) * 40 + cb * 16 + lr] = (f16)pv[cb][r];
    const f16x8 pf_ = *(const f16x8*)&Pw[lr * 40 + lg * 8];

#pragma unroll
    for (int dc = 0; dc < 8; dc++) {
      const f16x8 vf = *(const f16x8*)&VT[(dc * 16 + lr) * 40 + lg * 8];
#pragma unroll
      for (int r = 0; r < 4; r++) accd[dc][r] *= alpha[r];
      accd[dc] = __builtin_amdgcn_mfma_f32_16x16x32_f16(pf_, vf, accd[dc], 0, 0, 0);
    }

    __syncthreads();
    if (pf) writeKV();
    __syncthreads();
  }

#pragma unroll
  for (int dc = 0; dc < 8; dc++)
#pragma unroll
    for (int r = 0; r < 4; r++) {
      const int row = b * 1024 + q0 + w * 16 + lg * 4 + r;
      out[(size_t)row * 4096 + h * 128 + dc * 16 + lr] = (f16)(accd[dc][r] / l_r[r]);
    }
}

// ---------------- launch ----------------
extern "C" void kernel_launch(void* const* d_in, const int* in_sizes, int n_in,
                              void* d_out, int out_size, void* d_ws, size_t ws_size,
                              hipStream_t stream) {
  const float* x = (const float*)d_in[0];
  const float* cosT = (const float*)d_in[2];
  const float* sinT = (const float*)d_in[3];
  const int* wq = (const int*)d_in[4];
  const float* bq = (const float*)d_in[5];
  const float* sq = (const float*)d_in[6];
  const int* wk = (const int*)d_in[7];
  const float* bk = (const float*)d_in[8];
  const float* sk = (const float*)d_in[9];
  const int* wv = (const int*)d_in[10];
  const float* bv = (const float*)d_in[11];
  const float* sv = (const float*)d_in[12];
  const int* wo = (const int*)d_in[13];
  const float* so = (const float*)d_in[14];
  const int* sp = (const int*)d_in[15];

  char* ws = (char*)d_ws;
  f16* Acat = (f16*)ws;                        // x hi|lo [2048][8192]; later reused for Wo
  f16* Wcat = (f16*)(ws + 33554432);           // wq|wk|wv f16 [6144][4096]
  f16* XH = (f16*)(ws + 83886080);             // qkv hi [2048][6144]
  f16* XL = (f16*)(ws + 109051904);            // qkv lo
  f16* AO = (f16*)(ws + 134217728);            // attn out [2048][4096]
  float* biasv = (float*)(ws + 150994944);
  float* scalev = (float*)(ws + 151019520);

  hipFuncSetAttribute(reinterpret_cast<const void*>(&k_gemm9<128, 384, 0>),
                      hipFuncAttributeMaxDynamicSharedMemorySize, 131072);
  hipFuncSetAttribute(reinterpret_cast<const void*>(&k_gemm9<128, 256, 1>),
                      hipFuncAttributeMaxDynamicSharedMemorySize, 98304);

  k_prep_all<<<32768, 256, 0, stream>>>(x, wq, wk, wv, bq, bk, bv, sq, sk, sv,
                                        Acat, Wcat, biasv, scalev);

  // fused QKV projection + RoPE epilogue (split-x, K=8192, W wraps at 4096)
  k_gemm9<128, 384, 0><<<256, 512, 131072, stream>>>(
      Acat, Wcat, XH, XL, nullptr, scalev, biasv, nullptr, cosT, sinT, sp,
      6144, 8192, 4095, 4096, 16);

  f16* Wo_ = Acat;  // Acat dead after QKV GEMM
  k_cast_i32_f16<<<16384, 256, 0, stream>>>(wo, Wo_, 16777216);

  // attention: 512 blocks (QBLK=128), kvh-pinned XCD swizzle, reg-prefetch
  k_attn4<<<512, 512, 0, stream>>>(XH, XL, AO);

  // output projection -> f32; 16 x 16 = 256 blocks = exactly 1/CU
  k_gemm9<128, 256, 1><<<256, 512, 98304, stream>>>(
      AO, Wo_, nullptr, nullptr, (float*)d_out, nullptr, nullptr, so,
      nullptr, nullptr, nullptr, 4096, 4096, 0x7fffffff, 4096, 16);
}

// Round 14
// 442.664 us; speedup vs baseline: 1.0870x; 1.0766x over previous
//
#include <hip/hip_runtime.h>
#include <hip/hip_bf16.h>
#include <hip/hip_fp16.h>
#include <cstdint>

typedef _Float16 f16;
typedef _Float16 f16x8 __attribute__((ext_vector_type(8)));
typedef _Float16 f16x4 __attribute__((ext_vector_type(4)));
typedef float f32x4 __attribute__((ext_vector_type(4)));

#define DEV_INLINE __device__ __forceinline__

// async 16B/lane global->LDS. LDS dest is wave-uniform base + lane*16.
DEV_INLINE void async_ld16(const void* g, void* l) {
  __builtin_amdgcn_global_load_lds((const __attribute__((address_space(1))) void*)g,
                                   (__attribute__((address_space(3))) void*)l, 16, 0, 0);
}

template <int N>
DEV_INLINE void wait_vm() {
  static_assert(N >= 0 && N <= 12, "gate range");
  if constexpr (N == 0)  asm volatile("s_waitcnt vmcnt(0)" ::: "memory");
  if constexpr (N == 1)  asm volatile("s_waitcnt vmcnt(1)" ::: "memory");
  if constexpr (N == 2)  asm volatile("s_waitcnt vmcnt(2)" ::: "memory");
  if constexpr (N == 3)  asm volatile("s_waitcnt vmcnt(3)" ::: "memory");
  if constexpr (N == 4)  asm volatile("s_waitcnt vmcnt(4)" ::: "memory");
  if constexpr (N == 5)  asm volatile("s_waitcnt vmcnt(5)" ::: "memory");
  if constexpr (N == 6)  asm volatile("s_waitcnt vmcnt(6)" ::: "memory");
  if constexpr (N == 7)  asm volatile("s_waitcnt vmcnt(7)" ::: "memory");
  if constexpr (N == 8)  asm volatile("s_waitcnt vmcnt(8)" ::: "memory");
  if constexpr (N == 9)  asm volatile("s_waitcnt vmcnt(9)" ::: "memory");
  if constexpr (N == 10) asm volatile("s_waitcnt vmcnt(10)" ::: "memory");
  if constexpr (N == 11) asm volatile("s_waitcnt vmcnt(11)" ::: "memory");
  if constexpr (N == 12) asm volatile("s_waitcnt vmcnt(12)" ::: "memory");
}
DEV_INLINE void lgk0() {
  asm volatile("s_waitcnt lgkmcnt(0)" ::: "memory");
  __builtin_amdgcn_sched_barrier(0);
}

// ---------------- merged prep: x hi/lo split + Wcat cast + bias/scale ----------------
__global__ __launch_bounds__(256) void k_prep_all(
    const float* __restrict__ x,
    const int* __restrict__ wq, const int* __restrict__ wk, const int* __restrict__ wv,
    const float* __restrict__ bq, const float* __restrict__ bk, const float* __restrict__ bv,
    const float* __restrict__ sq, const float* __restrict__ sk, const float* __restrict__ sv,
    f16* __restrict__ acat, f16* __restrict__ wcat,
    float* __restrict__ bias_cat, float* __restrict__ scale_cat) {
  const int bid = blockIdx.x;
  if (bid < 8192) {
    int i = (bid * 256 + threadIdx.x) * 4;  // exactly covers 2048*4096
    float4 v = *(const float4*)&x[i];
    int row = i >> 12, col = i & 4095;
    f16 h0 = (f16)v.x, h1 = (f16)v.y, h2 = (f16)v.z, h3 = (f16)v.w;
    f16x4 hi = {h0, h1, h2, h3};
    f16x4 lo = {(f16)(v.x - (float)h0), (f16)(v.y - (float)h1),
                (f16)(v.z - (float)h2), (f16)(v.w - (float)h3)};
    size_t base = (size_t)row * 8192 + col;
    *(f16x4*)&acat[base] = hi;
    *(f16x4*)&acat[base + 4096] = lo;
  } else {
    int i = (bid - 8192) * 256 + threadIdx.x;
    if (i < 6291456) {
      int e = i * 4, row = e >> 12, col = e & 4095;
      int4 v;
      if (row < 4096)      v = *(const int4*)&wq[(size_t)row * 4096 + col];
      else if (row < 5120) v = *(const int4*)&wk[(size_t)(row - 4096) * 4096 + col];
      else                 v = *(const int4*)&wv[(size_t)(row - 5120) * 4096 + col];
      f16x4 o = {(f16)(float)v.x, (f16)(float)v.y, (f16)(float)v.z, (f16)(float)v.w};
      *(f16x4*)&wcat[e] = o;
    }
    if (i < 6144) {
      float b, s;
      if (i < 4096)      { b = bq[i];        s = sq[0]; }
      else if (i < 5120) { b = bk[i - 4096]; s = sk[0]; }
      else               { b = bv[i - 5120]; s = sv[0]; }
      bias_cat[i] = b;
      scale_cat[i] = s;
    }
  }
}

// int32 weights (values in [-127,127], exact in f16) -> f16
__global__ __launch_bounds__(256) void k_cast_i32_f16(const int* __restrict__ w,
                                                      f16* __restrict__ out, int n) {
  int i = (blockIdx.x * 256 + threadIdx.x) * 4;
  if (i >= n) return;
  int4 v = *(const int4*)&w[i];
  f16x4 o = {(f16)(float)v.x, (f16)(float)v.y, (f16)(float)v.z, (f16)(float)v.w};
  *(f16x4*)&out[i] = o;
}

// ---------------- GEMM v9: v8 body (proven) + fused-RoPE epilogue in MODE 0 ----------------
template <int BM, int BN, int MODE>
__global__ __launch_bounds__(512) void k_gemm9(
    const f16* __restrict__ A, const f16* __restrict__ W,
    f16* __restrict__ o_hi, f16* __restrict__ o_lo, float* __restrict__ o_f32,
    const float* __restrict__ scale_vec, const float* __restrict__ bias_vec,
    const float* __restrict__ scale_scalar,
    const float* __restrict__ cosT, const float* __restrict__ sinT,
    const int* __restrict__ sp,
    int N, int K, int kmask, int ldw, int nym) {
  constexpr int WM = 2, WN = 4;
  constexpr int MR = BM / WM / 16;      // 4
  constexpr int NR = BN / WN / 16;      // 6 (qkv) / 4 (oproj)
  constexpr int AKC = BM * 64;          // bytes per A kc-block
  constexpr int BKC = BN * 64;
  constexpr int SLOT = 2 * (AKC + BKC);
  constexpr int LAH = AKC / 8192;       // 1
  constexpr int LBH = BKC / 8192;       // 3 / 2
  constexpr int GS = 2 * (LAH + LBH);   // 8 / 6
  constexpr int G1 = LAH + LBH;         // 4 / 3
  extern __shared__ __align__(16) char lds[];

  const int t = threadIdx.x, w = t >> 6, ln = t & 63;
  const int lr = ln & 15, lg = ln >> 4;
  const int wn = w & 3, wm = w >> 2;

  // T1: bijective XCD swizzle (m204)
  const int nwg = gridDim.x;
  const int q8 = nwg >> 3, r8 = nwg & 7;
  const int xcd = blockIdx.x & 7, bidx = blockIdx.x >> 3;
  const int sid = (xcd < r8 ? xcd * (q8 + 1) : r8 * (q8 + 1) + (xcd - r8) * q8) + bidx;
  const int m0 = (sid % nym) * BM;
  const int n0 = (sid / nym) * BN;

  const f16* aSrc[LAH];
  const f16* bSrc[LBH];
#pragma unroll
  for (int l = 0; l < LAH; l++) {
    int ci = l * 512 + t, row = ci >> 2, c = ci & 3;
    aSrc[l] = A + (size_t)(m0 + row) * K + (c ^ ((row >> 1) & 3)) * 8;
  }
#pragma unroll
  for (int l = 0; l < LBH; l++) {
    int ci = l * 512 + t, row = ci >> 2, c = ci & 3;
    bSrc[l] = W + (size_t)(n0 + row) * ldw + (c ^ ((row >> 1) & 3)) * 8;
  }

  f32x4 acc[MR][NR] = {};
  f16x8 af[MR], bfa[NR];

  auto stageA = [&](int tt, int kc) {
    char* dst = lds + (tt & 1) * SLOT + kc * AKC;
    const int ko = tt * 64 + kc * 32;
#pragma unroll
    for (int l = 0; l < LAH; l++)
      async_ld16(aSrc[l] + ko, dst + (l * 512 + w * 64) * 16);
  };
  auto stageB = [&](int tt, int kc) {
    char* dst = lds + (tt & 1) * SLOT + 2 * AKC + kc * BKC;
    const int ko = ((tt * 64) & kmask) + kc * 32;
#pragma unroll
    for (int l = 0; l < LBH; l++)
      async_ld16(bSrc[l] + ko, dst + (l * 512 + w * 64) * 16);
  };
  auto readA = [&](int tt, int kc) {
    const char* base = lds + (tt & 1) * SLOT + kc * AKC;
#pragma unroll
    for (int mf = 0; mf < MR; mf++) {
      const int row = wm * (BM / WM) + mf * 16 + lr;
      af[mf] = *(const f16x8*)(base + row * 64 + (lg ^ ((row >> 1) & 3)) * 16);
    }
  };
  auto readBall = [&](int tt, int kc) {
    const char* base = lds + (tt & 1) * SLOT + 2 * AKC + kc * BKC;
#pragma unroll
    for (int nf = 0; nf < NR; nf++) {
      const int row = wn * (BN / WN) + nf * 16 + lr;
      bfa[nf] = *(const f16x8*)(base + row * 64 + (lg ^ ((row >> 1) & 3)) * 16);
    }
  };
  auto mma = [&]() {
    __builtin_amdgcn_s_setprio(1);
#pragma unroll
    for (int m = 0; m < MR; m++)
#pragma unroll
      for (int n = 0; n < NR; n++)
        acc[m][n] = __builtin_amdgcn_mfma_f32_16x16x32_f16(af[m], bfa[n], acc[m][n], 0, 0, 0);
    __builtin_amdgcn_s_setprio(0);
  };
  auto bar = [&]() { __builtin_amdgcn_s_barrier(); };

  const int NT = K >> 6;
  stageA(0, 0); stageB(0, 0); stageA(0, 1); stageB(0, 1);
  stageA(1, 0); stageB(1, 0);
  wait_vm<GS>();
  bar();

  for (int tt = 0; tt + 2 < NT; ++tt) {
    stageA(tt + 1, 1); stageB(tt + 1, 1);
    readA(tt, 0); readBall(tt, 0);
    wait_vm<GS>();
    bar(); lgk0(); mma(); bar();
    stageA(tt + 2, 0); stageB(tt + 2, 0);
    readA(tt, 1); readBall(tt, 1);
    wait_vm<GS>();
    bar(); lgk0(); mma(); bar();
  }
  {
    const int tt = NT - 2;
    stageA(tt + 1, 1); stageB(tt + 1, 1);
    readA(tt, 0); readBall(tt, 0);
    wait_vm<GS>();
    bar(); lgk0(); mma(); bar();
    readA(tt, 1); readBall(tt, 1);
    wait_vm<G1>();
    bar(); lgk0(); mma(); bar();
  }
  {
    const int tt = NT - 1;
    readA(tt, 0); readBall(tt, 0);
    wait_vm<0>();
    bar(); lgk0(); mma(); bar();
    readA(tt, 1); readBall(tt, 1);
    lgk0(); mma();
  }

  if constexpr (MODE == 0) {
    // fused RoPE epilogue (BM=128, BN=384 = 3 heads, head-aligned)
    float* xch = (float*)lds;             // [64][385] f32, padded
    const int sp0 = sp[0];
    for (int pass = 0; pass < 2; ++pass) {
      bar();  // all waves done with prior lds use
      if (wm == pass) {
#pragma unroll
        for (int n = 0; n < NR; n++) {
          const int col = wn * (BN / WN) + n * 16 + lr;
          const float sc = scale_vec[n0 + col];
          const float bs = bias_vec[n0 + col];
#pragma unroll
          for (int m = 0; m < MR; m++)
#pragma unroll
            for (int r2 = 0; r2 < 4; r2++) {
              const int row = m * 16 + lg * 4 + r2;  // 0..63 within pass
              xch[row * 385 + col] = acc[m][n][r2] * sc + bs;
            }
        }
      }
      bar();  // xch visible to all
      for (int j = 0; j < (64 * BN) / 512; j++) {
        const int idx = j * 512 + t;
        const int r = idx / BN;
        const int c = idx - r * BN;
        const int gr = m0 + pass * 64 + r;
        const int gcol = n0 + c;
        float v = xch[r * 385 + c];
        float o;
        if (gcol < 5120) {  // Q,K heads get RoPE; V cols pass through
          const int q = c & 127;
          const int pos = (gr & 1023) + sp0;
          const float cs = cosT[pos * 128 + q];
          const float sn = sinT[pos * 128 + q];
          const float vp = xch[r * 385 + ((q < 64) ? c + 64 : c - 64)];
          o = (q < 64) ? v * cs - vp * sn : v * cs + vp * sn;
        } else {
          o = v;
        }
        f16 h = (f16)o;
        o_hi[(size_t)gr * N + gcol] = h;
        o_lo[(size_t)gr * N + gcol] = (f16)(o - (float)h);
      }
    }
  } else {
#pragma unroll
    for (int n = 0; n < NR; n++) {
      const int col = n0 + wn * (BN / WN) + n * 16 + lr;
      const float sc = scale_scalar[0];
#pragma unroll
      for (int m = 0; m < MR; m++)
#pragma unroll
        for (int r2 = 0; r2 < 4; r2++) {
          const int row = m0 + wm * (BM / WM) + m * 16 + lg * 4 + r2;
          o_f32[(size_t)row * N + col] = acc[m][n][r2] * sc;
        }
    }
  }
}

// ---------------- flash attention v5: QBLK=128, kvh-pinned, heavy/light CU pairing ----------------
// id = ((qb*8 + b*4 + hg))*8 + kvh. kvh in low 3 bits pins the K/V stream to one
// XCD (unchanged). qb now in the HIGH bits of the stream index j: with in-order
// intra-XCD CU fill, CU c of an XCD receives j=c (qb=c>>3) and j=c+32 (qb=c>>3+4)
// -> per-CU causal work (qb+1)+(qb+5) in {6,8,10,12} vs old same-qb pairing max 16.
__global__ __launch_bounds__(512) void k_attn5(const f16* __restrict__ XH,
                                               const f16* __restrict__ XL,
                                               f16* __restrict__ out) {
  __shared__ __align__(16) f16 KsH[32 * 152];
  __shared__ __align__(16) f16 KsL[32 * 152];
  __shared__ __align__(16) f16 VT[128 * 40];
  __shared__ __align__(16) f16 Pb[8 * 16 * 40];
  const int t = threadIdx.x, w = t >> 6, l = t & 63;
  const int lr = l & 15, lg = l >> 4;
  const int id = blockIdx.x;
  const int kvh = id & 7;
  const int j = id >> 3;
  const int hg = j & 3;
  const int b = (j >> 2) & 1;
  const int qb = j >> 3;
  const int h = kvh * 4 + hg;
  const int q0 = qb * 128;
  const size_t rs_ = 6144;
  const f16* Qh = XH + ((size_t)(b * 1024 + q0)) * rs_ + h * 128;
  const f16* Ql_ = XL + ((size_t)(b * 1024 + q0)) * rs_ + h * 128;
  const f16* KhG = XH + ((size_t)(b * 1024)) * rs_ + 4096 + kvh * 128;
  const f16* KlG = XL + ((size_t)(b * 1024)) * rs_ + 4096 + kvh * 128;
  const f16* VG = XH + ((size_t)(b * 1024)) * rs_ + 5120 + kvh * 128;

  f16x8 qh[4], ql[4];
  {
    size_t qoff = (size_t)(w * 16 + lr) * rs_ + lg * 8;
#pragma unroll
    for (int c = 0; c < 4; c++) {
      qh[c] = *(const f16x8*)(Qh + qoff + c * 32);
      ql[c] = *(const f16x8*)(Ql_ + qoff + c * 32);
    }
  }
  f32x4 accd[8] = {};
  float m_r[4], l_r[4];
#pragma unroll
  for (int r = 0; r < 4; r++) { m_r[r] = -1e30f; l_r[r] = 0.f; }

  const int krow_s = t >> 4, kch = t & 15;
  const int vrow_s = t & 31, vd8 = t >> 5;
  f16x8 khr, klr, vr;
  auto loadKV = [&](int kv0) {
    size_t go = (size_t)(kv0 + krow_s) * rs_ + kch * 8;
    khr = *(const f16x8*)(KhG + go);
    klr = *(const f16x8*)(KlG + go);
    vr = *(const f16x8*)(VG + (size_t)(kv0 + vrow_s) * rs_ + vd8 * 8);
  };
  auto writeKV = [&]() {
    *(f16x8*)&KsH[krow_s * 152 + kch * 8] = khr;
    *(f16x8*)&KsL[krow_s * 152 + kch * 8] = klr;
#pragma unroll
    for (int jj = 0; jj < 8; jj++) VT[(vd8 * 8 + jj) * 40 + vrow_s] = vr[jj];
  };

  const int nkv = q0 + 128;
  const int NT = nkv >> 5;
  loadKV(0);
  wait_vm<0>();
  writeKV();
  __syncthreads();

  for (int tt = 0; tt < NT; ++tt) {
    const int kv0 = tt * 32;
    const bool pf = (tt + 1 < NT);
    if (pf) {
      loadKV(kv0 + 32);
      __builtin_amdgcn_sched_barrier(0);
    }

    f32x4 sc[2] = {};
#pragma unroll
    for (int cb = 0; cb < 2; cb++)
#pragma unroll
      for (int c = 0; c < 4; c++) {
        const f16x8 kh = *(const f16x8*)&KsH[(cb * 16 + lr) * 152 + c * 32 + lg * 8];
        const f16x8 kl = *(const f16x8*)&KsL[(cb * 16 + lr) * 152 + c * 32 + lg * 8];
        sc[cb] = __builtin_amdgcn_mfma_f32_16x16x32_f16(qh[c], kh, sc[cb], 0, 0, 0);
        sc[cb] = __builtin_amdgcn_mfma_f32_16x16x32_f16(qh[c], kl, sc[cb], 0, 0, 0);
        sc[cb] = __builtin_amdgcn_mfma_f32_16x16x32_f16(ql[c], kh, sc[cb], 0, 0, 0);
      }

    const float scale = 0.088388347648318447f;
    float alpha[4], pv[2][4];
#pragma unroll
    for (int r = 0; r < 4; r++) {
      const int qg = q0 + w * 16 + lg * 4 + r;
      float mx = -1e30f;
#pragma unroll
      for (int cb = 0; cb < 2; cb++) {
        const int kg = kv0 + cb * 16 + lr;
        float s = sc[cb][r] * scale;
        s = (kg <= qg) ? s : -1e30f;
        pv[cb][r] = s;
        mx = fmaxf(mx, s);
      }
      mx = fmaxf(mx, __shfl_xor(mx, 1));
      mx = fmaxf(mx, __shfl_xor(mx, 2));
      mx = fmaxf(mx, __shfl_xor(mx, 4));
      mx = fmaxf(mx, __shfl_xor(mx, 8));
      const float mn = fmaxf(m_r[r], mx);
      alpha[r] = __expf(m_r[r] - mn);
      m_r[r] = mn;
      float rsum = 0.f;
#pragma unroll
      for (int cb = 0; cb < 2; cb++) {
        const int kg = kv0 + cb * 16 + lr;
        const float p = (kg <= qg) ? __expf(pv[cb][r] - mn) : 0.f;
        pv[cb][r] = p;
        rsum += p;
      }
      rsum += __shfl_xor(rsum, 1);
      rsum += __shfl_xor(rsum, 2);
      rsum += __shfl_xor(rsum, 4);
      rsum += __shfl_xor(rsum, 8);
      l_r[r] = l_r[r] * alpha[r] + rsum;
    }

    f16* Pw = &Pb[w * 16 * 40];
#pragma unroll
    for (int r = 0; r < 4; r++)
#pragma unroll
      for (int cb = 0; cb < 2; cb++)
        Pw[(lg * 4 + r) * 40 + cb * 16 + lr] = (f16)pv[cb][r];
    const f16x8 pf_ = *(const f16x8*)&Pw[lr * 40 + lg * 8];

#pragma unroll
    for (int dc = 0; dc < 8; dc++) {
      const f16x8 vf = *(const f16x8*)&VT[(dc * 16 + lr) * 40 + lg * 8];
#pragma unroll
      for (int r = 0; r < 4; r++) accd[dc][r] *= alpha[r];
      accd[dc] = __builtin_amdgcn_mfma_f32_16x16x32_f16(pf_, vf, accd[dc], 0, 0, 0);
    }

    __syncthreads();
    if (pf) writeKV();
    __syncthreads();
  }

#pragma unroll
  for (int dc = 0; dc < 8; dc++)
#pragma unroll
    for (int r = 0; r < 4; r++) {
      const int row = b * 1024 + q0 + w * 16 + lg * 4 + r;
      out[(size_t)row * 4096 + h * 128 + dc * 16 + lr] = (f16)(accd[dc][r] / l_r[r]);
    }
}

// ---------------- launch ----------------
extern "C" void kernel_launch(void* const* d_in, const int* in_sizes, int n_in,
                              void* d_out, int out_size, void* d_ws, size_t ws_size,
                              hipStream_t stream) {
  const float* x = (const float*)d_in[0];
  const float* cosT = (const float*)d_in[2];
  const float* sinT = (const float*)d_in[3];
  const int* wq = (const int*)d_in[4];
  const float* bq = (const float*)d_in[5];
  const float* sq = (const float*)d_in[6];
  const int* wk = (const int*)d_in[7];
  const float* bk = (const float*)d_in[8];
  const float* sk = (const float*)d_in[9];
  const int* wv = (const int*)d_in[10];
  const float* bv = (const float*)d_in[11];
  const float* sv = (const float*)d_in[12];
  const int* wo = (const int*)d_in[13];
  const float* so = (const float*)d_in[14];
  const int* sp = (const int*)d_in[15];

  char* ws = (char*)d_ws;
  f16* Acat = (f16*)ws;                        // x hi|lo [2048][8192]; later reused for Wo
  f16* Wcat = (f16*)(ws + 33554432);           // wq|wk|wv f16 [6144][4096]
  f16* XH = (f16*)(ws + 83886080);             // qkv hi [2048][6144]
  f16* XL = (f16*)(ws + 109051904);            // qkv lo
  f16* AO = (f16*)(ws + 134217728);            // attn out [2048][4096]
  float* biasv = (float*)(ws + 150994944);
  float* scalev = (float*)(ws + 151019520);

  hipFuncSetAttribute(reinterpret_cast<const void*>(&k_gemm9<128, 384, 0>),
                      hipFuncAttributeMaxDynamicSharedMemorySize, 131072);
  hipFuncSetAttribute(reinterpret_cast<const void*>(&k_gemm9<128, 256, 1>),
                      hipFuncAttributeMaxDynamicSharedMemorySize, 98304);

  k_prep_all<<<32768, 256, 0, stream>>>(x, wq, wk, wv, bq, bk, bv, sq, sk, sv,
                                        Acat, Wcat, biasv, scalev);

  // fused QKV projection + RoPE epilogue (split-x, K=8192, W wraps at 4096)
  k_gemm9<128, 384, 0><<<256, 512, 131072, stream>>>(
      Acat, Wcat, XH, XL, nullptr, scalev, biasv, nullptr, cosT, sinT, sp,
      6144, 8192, 4095, 4096, 16);

  f16* Wo_ = Acat;  // Acat dead after QKV GEMM
  k_cast_i32_f16<<<16384, 256, 0, stream>>>(wo, Wo_, 16777216);

  // attention: 512 blocks, kvh-pinned XCD swizzle + heavy/light CU pairing
  k_attn5<<<512, 512, 0, stream>>>(XH, XL, AO);

  // output projection -> f32; 16 x 16 = 256 blocks = exactly 1/CU
  k_gemm9<128, 256, 1><<<256, 512, 98304, stream>>>(
      AO, Wo_, nullptr, nullptr, (float*)d_out, nullptr, nullptr, so,
      nullptr, nullptr, nullptr, 4096, 4096, 0x7fffffff, 4096, 16);
}

// Round 15
// 421.219 us; speedup vs baseline: 1.1424x; 1.0509x over previous
//
#include <hip/hip_runtime.h>
#include <hip/hip_bf16.h>
#include <hip/hip_fp16.h>
#include <cstdint>

typedef _Float16 f16;
typedef _Float16 f16x8 __attribute__((ext_vector_type(8)));
typedef _Float16 f16x4 __attribute__((ext_vector_type(4)));
typedef float f32x4 __attribute__((ext_vector_type(4)));

#define DEV_INLINE __device__ __forceinline__

// async 16B/lane global->LDS. LDS dest is wave-uniform base + lane*16.
DEV_INLINE void async_ld16(const void* g, void* l) {
  __builtin_amdgcn_global_load_lds((const __attribute__((address_space(1))) void*)g,
                                   (__attribute__((address_space(3))) void*)l, 16, 0, 0);
}

template <int N>
DEV_INLINE void wait_vm() {
  static_assert(N >= 0 && N <= 12, "gate range");
  if constexpr (N == 0)  asm volatile("s_waitcnt vmcnt(0)" ::: "memory");
  if constexpr (N == 1)  asm volatile("s_waitcnt vmcnt(1)" ::: "memory");
  if constexpr (N == 2)  asm volatile("s_waitcnt vmcnt(2)" ::: "memory");
  if constexpr (N == 3)  asm volatile("s_waitcnt vmcnt(3)" ::: "memory");
  if constexpr (N == 4)  asm volatile("s_waitcnt vmcnt(4)" ::: "memory");
  if constexpr (N == 5)  asm volatile("s_waitcnt vmcnt(5)" ::: "memory");
  if constexpr (N == 6)  asm volatile("s_waitcnt vmcnt(6)" ::: "memory");
  if constexpr (N == 7)  asm volatile("s_waitcnt vmcnt(7)" ::: "memory");
  if constexpr (N == 8)  asm volatile("s_waitcnt vmcnt(8)" ::: "memory");
  if constexpr (N == 9)  asm volatile("s_waitcnt vmcnt(9)" ::: "memory");
  if constexpr (N == 10) asm volatile("s_waitcnt vmcnt(10)" ::: "memory");
  if constexpr (N == 11) asm volatile("s_waitcnt vmcnt(11)" ::: "memory");
  if constexpr (N == 12) asm volatile("s_waitcnt vmcnt(12)" ::: "memory");
}
DEV_INLINE void lgk0() {
  asm volatile("s_waitcnt lgkmcnt(0)" ::: "memory");
  __builtin_amdgcn_sched_barrier(0);
}

// ---------------- merged prep: x hi/lo split + Wcat cast + bias/scale ----------------
__global__ __launch_bounds__(256) void k_prep_all(
    const float* __restrict__ x,
    const int* __restrict__ wq, const int* __restrict__ wk, const int* __restrict__ wv,
    const float* __restrict__ bq, const float* __restrict__ bk, const float* __restrict__ bv,
    const float* __restrict__ sq, const float* __restrict__ sk, const float* __restrict__ sv,
    f16* __restrict__ acat, f16* __restrict__ wcat,
    float* __restrict__ bias_cat, float* __restrict__ scale_cat) {
  const int bid = blockIdx.x;
  if (bid < 8192) {
    int i = (bid * 256 + threadIdx.x) * 4;  // exactly covers 2048*4096
    float4 v = *(const float4*)&x[i];
    int row = i >> 12, col = i & 4095;
    f16 h0 = (f16)v.x, h1 = (f16)v.y, h2 = (f16)v.z, h3 = (f16)v.w;
    f16x4 hi = {h0, h1, h2, h3};
    f16x4 lo = {(f16)(v.x - (float)h0), (f16)(v.y - (float)h1),
                (f16)(v.z - (float)h2), (f16)(v.w - (float)h3)};
    size_t base = (size_t)row * 8192 + col;
    *(f16x4*)&acat[base] = hi;
    *(f16x4*)&acat[base + 4096] = lo;
  } else {
    int i = (bid - 8192) * 256 + threadIdx.x;
    if (i < 6291456) {
      int e = i * 4, row = e >> 12, col = e & 4095;
      int4 v;
      if (row < 4096)      v = *(const int4*)&wq[(size_t)row * 4096 + col];
      else if (row < 5120) v = *(const int4*)&wk[(size_t)(row - 4096) * 4096 + col];
      else                 v = *(const int4*)&wv[(size_t)(row - 5120) * 4096 + col];
      f16x4 o = {(f16)(float)v.x, (f16)(float)v.y, (f16)(float)v.z, (f16)(float)v.w};
      *(f16x4*)&wcat[e] = o;
    }
    if (i < 6144) {
      float b, s;
      if (i < 4096)      { b = bq[i];        s = sq[0]; }
      else if (i < 5120) { b = bk[i - 4096]; s = sk[0]; }
      else               { b = bv[i - 5120]; s = sv[0]; }
      bias_cat[i] = b;
      scale_cat[i] = s;
    }
  }
}

// int32 weights (values in [-127,127], exact in f16) -> f16
__global__ __launch_bounds__(256) void k_cast_i32_f16(const int* __restrict__ w,
                                                      f16* __restrict__ out, int n) {
  int i = (blockIdx.x * 256 + threadIdx.x) * 4;
  if (i >= n) return;
  int4 v = *(const int4*)&w[i];
  f16x4 o = {(f16)(float)v.x, (f16)(float)v.y, (f16)(float)v.z, (f16)(float)v.w};
  *(f16x4*)&out[i] = o;
}

// ---------------- GEMM v9: v8 body (proven) + fused-RoPE epilogue in MODE 0 ----------------
template <int BM, int BN, int MODE>
__global__ __launch_bounds__(512) void k_gemm9(
    const f16* __restrict__ A, const f16* __restrict__ W,
    f16* __restrict__ o_hi, f16* __restrict__ o_lo, float* __restrict__ o_f32,
    const float* __restrict__ scale_vec, const float* __restrict__ bias_vec,
    const float* __restrict__ scale_scalar,
    const float* __restrict__ cosT, const float* __restrict__ sinT,
    const int* __restrict__ sp,
    int N, int K, int kmask, int ldw, int nym) {
  constexpr int WM = 2, WN = 4;
  constexpr int MR = BM / WM / 16;      // 4
  constexpr int NR = BN / WN / 16;      // 6 (qkv) / 4 (oproj)
  constexpr int AKC = BM * 64;          // bytes per A kc-block
  constexpr int BKC = BN * 64;
  constexpr int SLOT = 2 * (AKC + BKC);
  constexpr int LAH = AKC / 8192;       // 1
  constexpr int LBH = BKC / 8192;       // 3 / 2
  constexpr int GS = 2 * (LAH + LBH);   // 8 / 6
  constexpr int G1 = LAH + LBH;         // 4 / 3
  extern __shared__ __align__(16) char lds[];

  const int t = threadIdx.x, w = t >> 6, ln = t & 63;
  const int lr = ln & 15, lg = ln >> 4;
  const int wn = w & 3, wm = w >> 2;

  // T1: bijective XCD swizzle (m204)
  const int nwg = gridDim.x;
  const int q8 = nwg >> 3, r8 = nwg & 7;
  const int xcd = blockIdx.x & 7, bidx = blockIdx.x >> 3;
  const int sid = (xcd < r8 ? xcd * (q8 + 1) : r8 * (q8 + 1) + (xcd - r8) * q8) + bidx;
  const int m0 = (sid % nym) * BM;
  const int n0 = (sid / nym) * BN;

  const f16* aSrc[LAH];
  const f16* bSrc[LBH];
#pragma unroll
  for (int l = 0; l < LAH; l++) {
    int ci = l * 512 + t, row = ci >> 2, c = ci & 3;
    aSrc[l] = A + (size_t)(m0 + row) * K + (c ^ ((row >> 1) & 3)) * 8;
  }
#pragma unroll
  for (int l = 0; l < LBH; l++) {
    int ci = l * 512 + t, row = ci >> 2, c = ci & 3;
    bSrc[l] = W + (size_t)(n0 + row) * ldw + (c ^ ((row >> 1) & 3)) * 8;
  }

  f32x4 acc[MR][NR] = {};
  f16x8 af[MR], bfa[NR];

  auto stageA = [&](int tt, int kc) {
    char* dst = lds + (tt & 1) * SLOT + kc * AKC;
    const int ko = tt * 64 + kc * 32;
#pragma unroll
    for (int l = 0; l < LAH; l++)
      async_ld16(aSrc[l] + ko, dst + (l * 512 + w * 64) * 16);
  };
  auto stageB = [&](int tt, int kc) {
    char* dst = lds + (tt & 1) * SLOT + 2 * AKC + kc * BKC;
    const int ko = ((tt * 64) & kmask) + kc * 32;
#pragma unroll
    for (int l = 0; l < LBH; l++)
      async_ld16(bSrc[l] + ko, dst + (l * 512 + w * 64) * 16);
  };
  auto readA = [&](int tt, int kc) {
    const char* base = lds + (tt & 1) * SLOT + kc * AKC;
#pragma unroll
    for (int mf = 0; mf < MR; mf++) {
      const int row = wm * (BM / WM) + mf * 16 + lr;
      af[mf] = *(const f16x8*)(base + row * 64 + (lg ^ ((row >> 1) & 3)) * 16);
    }
  };
  auto readBall = [&](int tt, int kc) {
    const char* base = lds + (tt & 1) * SLOT + 2 * AKC + kc * BKC;
#pragma unroll
    for (int nf = 0; nf < NR; nf++) {
      const int row = wn * (BN / WN) + nf * 16 + lr;
      bfa[nf] = *(const f16x8*)(base + row * 64 + (lg ^ ((row >> 1) & 3)) * 16);
    }
  };
  auto mma = [&]() {
    __builtin_amdgcn_s_setprio(1);
#pragma unroll
    for (int m = 0; m < MR; m++)
#pragma unroll
      for (int n = 0; n < NR; n++)
        acc[m][n] = __builtin_amdgcn_mfma_f32_16x16x32_f16(af[m], bfa[n], acc[m][n], 0, 0, 0);
    __builtin_amdgcn_s_setprio(0);
  };
  auto bar = [&]() { __builtin_amdgcn_s_barrier(); };

  const int NT = K >> 6;
  stageA(0, 0); stageB(0, 0); stageA(0, 1); stageB(0, 1);
  stageA(1, 0); stageB(1, 0);
  wait_vm<GS>();
  bar();

  for (int tt = 0; tt + 2 < NT; ++tt) {
    stageA(tt + 1, 1); stageB(tt + 1, 1);
    readA(tt, 0); readBall(tt, 0);
    wait_vm<GS>();
    bar(); lgk0(); mma(); bar();
    stageA(tt + 2, 0); stageB(tt + 2, 0);
    readA(tt, 1); readBall(tt, 1);
    wait_vm<GS>();
    bar(); lgk0(); mma(); bar();
  }
  {
    const int tt = NT - 2;
    stageA(tt + 1, 1); stageB(tt + 1, 1);
    readA(tt, 0); readBall(tt, 0);
    wait_vm<GS>();
    bar(); lgk0(); mma(); bar();
    readA(tt, 1); readBall(tt, 1);
    wait_vm<G1>();
    bar(); lgk0(); mma(); bar();
  }
  {
    const int tt = NT - 1;
    readA(tt, 0); readBall(tt, 0);
    wait_vm<0>();
    bar(); lgk0(); mma(); bar();
    readA(tt, 1); readBall(tt, 1);
    lgk0(); mma();
  }

  if constexpr (MODE == 0) {
    // fused RoPE epilogue (BM=128, BN=384 = 3 heads, head-aligned)
    float* xch = (float*)lds;             // [64][385] f32, padded
    const int sp0 = sp[0];
    for (int pass = 0; pass < 2; ++pass) {
      bar();  // all waves done with prior lds use
      if (wm == pass) {
#pragma unroll
        for (int n = 0; n < NR; n++) {
          const int col = wn * (BN / WN) + n * 16 + lr;
          const float sc = scale_vec[n0 + col];
          const float bs = bias_vec[n0 + col];
#pragma unroll
          for (int m = 0; m < MR; m++)
#pragma unroll
            for (int r2 = 0; r2 < 4; r2++) {
              const int row = m * 16 + lg * 4 + r2;  // 0..63 within pass
              xch[row * 385 + col] = acc[m][n][r2] * sc + bs;
            }
        }
      }
      bar();  // xch visible to all
      for (int j = 0; j < (64 * BN) / 512; j++) {
        const int idx = j * 512 + t;
        const int r = idx / BN;
        const int c = idx - r * BN;
        const int gr = m0 + pass * 64 + r;
        const int gcol = n0 + c;
        float v = xch[r * 385 + c];
        float o;
        if (gcol < 5120) {  // Q,K heads get RoPE; V cols pass through
          const int q = c & 127;
          const int pos = (gr & 1023) + sp0;
          const float cs = cosT[pos * 128 + q];
          const float sn = sinT[pos * 128 + q];
          const float vp = xch[r * 385 + ((q < 64) ? c + 64 : c - 64)];
          o = (q < 64) ? v * cs - vp * sn : v * cs + vp * sn;
        } else {
          o = v;
        }
        f16 h = (f16)o;
        o_hi[(size_t)gr * N + gcol] = h;
        o_lo[(size_t)gr * N + gcol] = (f16)(o - (float)h);
      }
    }
  } else {
#pragma unroll
    for (int n = 0; n < NR; n++) {
      const int col = n0 + wn * (BN / WN) + n * 16 + lr;
      const float sc = scale_scalar[0];
#pragma unroll
      for (int m = 0; m < MR; m++)
#pragma unroll
        for (int r2 = 0; r2 < 4; r2++) {
          const int row = m0 + wm * (BM / WM) + m * 16 + lg * 4 + r2;
          o_f32[(size_t)row * N + col] = acc[m][n][r2] * sc;
        }
    }
  }
}

// ---------------- flash attention v6: kvh-pinned + MIRRORED qb pairing ----------------
// id = (j)*8 + kvh; j in 0..63 per batch of streams. half = j>>5, jj = j&31:
//   qb = half ? 7 - (jj>>3) : (jj>>3); hg = jj&3; b = (jj>>2)&1.
// With in-order intra-XCD CU fill, CU c receives j=c and j=c+32 whose causal
// work is (qb+1) + (8-qb) = 9 units EXACTLY for every CU (round-14's pairing
// had {6,8,10,12}; this flattens the makespan fully). kvh pin unchanged.
__global__ __launch_bounds__(512) void k_attn6(const f16* __restrict__ XH,
                                               const f16* __restrict__ XL,
                                               f16* __restrict__ out) {
  __shared__ __align__(16) f16 KsH[32 * 152];
  __shared__ __align__(16) f16 KsL[32 * 152];
  __shared__ __align__(16) f16 VT[128 * 40];
  __shared__ __align__(16) f16 Pb[8 * 16 * 40];
  const int t = threadIdx.x, w = t >> 6, l = t & 63;
  const int lr = l & 15, lg = l >> 4;
  const int id = blockIdx.x;
  const int kvh = id & 7;
  const int j = id >> 3;
  const int half = j >> 5;
  const int jj = j & 31;
  const int qb = half ? 7 - (jj >> 3) : (jj >> 3);
  const int hg = jj & 3;
  const int b = (jj >> 2) & 1;
  const int h = kvh * 4 + hg;
  const int q0 = qb * 128;
  const size_t rs_ = 6144;
  const f16* Qh = XH + ((size_t)(b * 1024 + q0)) * rs_ + h * 128;
  const f16* Ql_ = XL + ((size_t)(b * 1024 + q0)) * rs_ + h * 128;
  const f16* KhG = XH + ((size_t)(b * 1024)) * rs_ + 4096 + kvh * 128;
  const f16* KlG = XL + ((size_t)(b * 1024)) * rs_ + 4096 + kvh * 128;
  const f16* VG = XH + ((size_t)(b * 1024)) * rs_ + 5120 + kvh * 128;

  f16x8 qh[4], ql[4];
  {
    size_t qoff = (size_t)(w * 16 + lr) * rs_ + lg * 8;
#pragma unroll
    for (int c = 0; c < 4; c++) {
      qh[c] = *(const f16x8*)(Qh + qoff + c * 32);
      ql[c] = *(const f16x8*)(Ql_ + qoff + c * 32);
    }
  }
  f32x4 accd[8] = {};
  float m_r[4], l_r[4];
#pragma unroll
  for (int r = 0; r < 4; r++) { m_r[r] = -1e30f; l_r[r] = 0.f; }

  const int krow_s = t >> 4, kch = t & 15;
  const int vrow_s = t & 31, vd8 = t >> 5;
  f16x8 khr, klr, vr;
  auto loadKV = [&](int kv0) {
    size_t go = (size_t)(kv0 + krow_s) * rs_ + kch * 8;
    khr = *(const f16x8*)(KhG + go);
    klr = *(const f16x8*)(KlG + go);
    vr = *(const f16x8*)(VG + (size_t)(kv0 + vrow_s) * rs_ + vd8 * 8);
  };
  auto writeKV = [&]() {
    *(f16x8*)&KsH[krow_s * 152 + kch * 8] = khr;
    *(f16x8*)&KsL[krow_s * 152 + kch * 8] = klr;
#pragma unroll
    for (int jj2 = 0; jj2 < 8; jj2++) VT[(vd8 * 8 + jj2) * 40 + vrow_s] = vr[jj2];
  };

  const int nkv = q0 + 128;
  const int NT = nkv >> 5;
  loadKV(0);
  wait_vm<0>();
  writeKV();
  __syncthreads();

  for (int tt = 0; tt < NT; ++tt) {
    const int kv0 = tt * 32;
    const bool pf = (tt + 1 < NT);
    if (pf) {
      loadKV(kv0 + 32);
      __builtin_amdgcn_sched_barrier(0);
    }

    f32x4 sc[2] = {};
#pragma unroll
    for (int cb = 0; cb < 2; cb++)
#pragma unroll
      for (int c = 0; c < 4; c++) {
        const f16x8 kh = *(const f16x8*)&KsH[(cb * 16 + lr) * 152 + c * 32 + lg * 8];
        const f16x8 kl = *(const f16x8*)&KsL[(cb * 16 + lr) * 152 + c * 32 + lg * 8];
        sc[cb] = __builtin_amdgcn_mfma_f32_16x16x32_f16(qh[c], kh, sc[cb], 0, 0, 0);
        sc[cb] = __builtin_amdgcn_mfma_f32_16x16x32_f16(qh[c], kl, sc[cb], 0, 0, 0);
        sc[cb] = __builtin_amdgcn_mfma_f32_16x16x32_f16(ql[c], kh, sc[cb], 0, 0, 0);
      }

    const float scale = 0.088388347648318447f;
    float alpha[4], pv[2][4];
#pragma unroll
    for (int r = 0; r < 4; r++) {
      const int qg = q0 + w * 16 + lg * 4 + r;
      float mx = -1e30f;
#pragma unroll
      for (int cb = 0; cb < 2; cb++) {
        const int kg = kv0 + cb * 16 + lr;
        float s = sc[cb][r] * scale;
        s = (kg <= qg) ? s : -1e30f;
        pv[cb][r] = s;
        mx = fmaxf(mx, s);
      }
      mx = fmaxf(mx, __shfl_xor(mx, 1));
      mx = fmaxf(mx, __shfl_xor(mx, 2));
      mx = fmaxf(mx, __shfl_xor(mx, 4));
      mx = fmaxf(mx, __shfl_xor(mx, 8));
      const float mn = fmaxf(m_r[r], mx);
      alpha[r] = __expf(m_r[r] - mn);
      m_r[r] = mn;
      float rsum = 0.f;
#pragma unroll
      for (int cb = 0; cb < 2; cb++) {
        const int kg = kv0 + cb * 16 + lr;
        const float p = (kg <= qg) ? __expf(pv[cb][r] - mn) : 0.f;
        pv[cb][r] = p;
        rsum += p;
      }
      rsum += __shfl_xor(rsum, 1);
      rsum += __shfl_xor(rsum, 2);
      rsum += __shfl_xor(rsum, 4);
      rsum += __shfl_xor(rsum, 8);
      l_r[r] = l_r[r] * alpha[r] + rsum;
    }

    f16* Pw = &Pb[w * 16 * 40];
#pragma unroll
    for (int r = 0; r < 4; r++)
#pragma unroll
      for (int cb = 0; cb < 2; cb++)
        Pw[(lg * 4 + r) * 40 + cb * 16 + lr] = (f16)pv[cb][r];
    const f16x8 pf_ = *(const f16x8*)&Pw[lr * 40 + lg * 8];

#pragma unroll
    for (int dc = 0; dc < 8; dc++) {
      const f16x8 vf = *(const f16x8*)&VT[(dc * 16 + lr) * 40 + lg * 8];
#pragma unroll
      for (int r = 0; r < 4; r++) accd[dc][r] *= alpha[r];
      accd[dc] = __builtin_amdgcn_mfma_f32_16x16x32_f16(pf_, vf, accd[dc], 0, 0, 0);
    }

    __syncthreads();
    if (pf) writeKV();
    __syncthreads();
  }

#pragma unroll
  for (int dc = 0; dc < 8; dc++)
#pragma unroll
    for (int r = 0; r < 4; r++) {
      const int row = b * 1024 + q0 + w * 16 + lg * 4 + r;
      out[(size_t)row * 4096 + h * 128 + dc * 16 + lr] = (f16)(accd[dc][r] / l_r[r]);
    }
}

// ---------------- launch ----------------
extern "C" void kernel_launch(void* const* d_in, const int* in_sizes, int n_in,
                              void* d_out, int out_size, void* d_ws, size_t ws_size,
                              hipStream_t stream) {
  const float* x = (const float*)d_in[0];
  const float* cosT = (const float*)d_in[2];
  const float* sinT = (const float*)d_in[3];
  const int* wq = (const int*)d_in[4];
  const float* bq = (const float*)d_in[5];
  const float* sq = (const float*)d_in[6];
  const int* wk = (const int*)d_in[7];
  const float* bk = (const float*)d_in[8];
  const float* sk = (const float*)d_in[9];
  const int* wv = (const int*)d_in[10];
  const float* bv = (const float*)d_in[11];
  const float* sv = (const float*)d_in[12];
  const int* wo = (const int*)d_in[13];
  const float* so = (const float*)d_in[14];
  const int* sp = (const int*)d_in[15];

  char* ws = (char*)d_ws;
  f16* Acat = (f16*)ws;                        // x hi|lo [2048][8192]; later reused for Wo
  f16* Wcat = (f16*)(ws + 33554432);           // wq|wk|wv f16 [6144][4096]
  f16* XH = (f16*)(ws + 83886080);             // qkv hi [2048][6144]
  f16* XL = (f16*)(ws + 109051904);            // qkv lo
  f16* AO = (f16*)(ws + 134217728);            // attn out [2048][4096]
  float* biasv = (float*)(ws + 150994944);
  float* scalev = (float*)(ws + 151019520);

  hipFuncSetAttribute(reinterpret_cast<const void*>(&k_gemm9<128, 384, 0>),
                      hipFuncAttributeMaxDynamicSharedMemorySize, 131072);
  hipFuncSetAttribute(reinterpret_cast<const void*>(&k_gemm9<128, 256, 1>),
                      hipFuncAttributeMaxDynamicSharedMemorySize, 98304);

  k_prep_all<<<32768, 256, 0, stream>>>(x, wq, wk, wv, bq, bk, bv, sq, sk, sv,
                                        Acat, Wcat, biasv, scalev);

  // fused QKV projection + RoPE epilogue (split-x, K=8192, W wraps at 4096)
  k_gemm9<128, 384, 0><<<256, 512, 131072, stream>>>(
      Acat, Wcat, XH, XL, nullptr, scalev, biasv, nullptr, cosT, sinT, sp,
      6144, 8192, 4095, 4096, 16);

  f16* Wo_ = Acat;  // Acat dead after QKV GEMM
  k_cast_i32_f16<<<16384, 256, 0, stream>>>(wo, Wo_, 16777216);

  // attention: 512 blocks, kvh-pinned XCD swizzle + mirrored qb pairing (9 units/CU)
  k_attn6<<<512, 512, 0, stream>>>(XH, XL, AO);

  // output projection -> f32; 16 x 16 = 256 blocks = exactly 1/CU
  k_gemm9<128, 256, 1><<<256, 512, 98304, stream>>>(
      AO, Wo_, nullptr, nullptr, (float*)d_out, nullptr, nullptr, so,
      nullptr, nullptr, nullptr, 4096, 4096, 0x7fffffff, 4096, 16);
}